// Round 1
// baseline (139.063 us; speedup 1.0000x reference)
//
#include <hip/hip_runtime.h>

#define GS   16                 // S-table grid points per axis
#define GB   64                 // bias-table grid points
#define HDIM 256
#define PTS  4                  // grid points per build block
#define SOFF (4 * GS * GS * 12) // float offset of bias tables in ws

// ---------------------------------------------------------------------------
// Kernel 1: tabulate the pair MLP S(x0,x1) on a GS x GS grid for each of the 4
// layers (entry padded to 12 floats), and the two bias MLPs bq(m), bp(m) on a
// GB grid (entry padded to 4 floats).  Each block evaluates PTS grid points:
// phase A computes h0 (one element per thread), phase B does the 256x256
// hidden matmul with coalesced W1 rows + LDS-broadcast h0, phase C reduces the
// 256-long dot products for the small output layer with wave shuffles.
// ---------------------------------------------------------------------------
__global__ __launch_bounds__(256) void build_tables(
    const float* __restrict__ sW0, const float* __restrict__ sb0,
    const float* __restrict__ sW1, const float* __restrict__ sb1,
    const float* __restrict__ sW2, const float* __restrict__ sb2,
    const float* __restrict__ qW0, const float* __restrict__ qb0,
    const float* __restrict__ qW1, const float* __restrict__ qb1,
    const float* __restrict__ qW2, const float* __restrict__ qb2,
    const float* __restrict__ kW0, const float* __restrict__ kb0,
    const float* __restrict__ kW1, const float* __restrict__ kb1,
    const float* __restrict__ kW2, const float* __restrict__ kb2,
    float* __restrict__ ws)
{
    const int t  = threadIdx.x;
    const int bx = blockIdx.x;
    __shared__ float h0s[PTS][HDIM];
    __shared__ float red[4][PTS * 9];

    if (bx < (256 / PTS) * 4) {
        // ---------------- S table: 64 blocks per layer ----------------
        const int l  = bx / (256 / PTS);
        const int p0 = (bx % (256 / PTS)) * PTS;
        const float* W0 = sW0 + l * 2 * HDIM;
        const float* W1 = sW1 + l * HDIM * HDIM;
        const float b0v = sb0[l * HDIM + t];
        const float b1v = sb1[l * HDIM + t];

        #pragma unroll
        for (int pp = 0; pp < PTS; pp++) {
            int pt   = p0 + pp;
            float x0 = (float)(pt >> 4) * (1.0f / (GS - 1)); // first MLP input (m_j axis)
            float x1 = (float)(pt & 15) * (1.0f / (GS - 1)); // second MLP input (m_i axis)
            h0s[pp][t] = tanhf(x0 * W0[t] + x1 * W0[HDIM + t] + b0v);
        }
        __syncthreads();

        float acc[PTS];
        #pragma unroll
        for (int pp = 0; pp < PTS; pp++) acc[pp] = b1v;
        for (int k = 0; k < HDIM; k += 4) {
            float w0 = W1[(k + 0) * HDIM + t];
            float w1 = W1[(k + 1) * HDIM + t];
            float w2 = W1[(k + 2) * HDIM + t];
            float w3 = W1[(k + 3) * HDIM + t];
            #pragma unroll
            for (int pp = 0; pp < PTS; pp++) {
                float4 h = *(const float4*)&h0s[pp][k];  // broadcast read
                acc[pp] += h.x * w0 + h.y * w1 + h.z * w2 + h.w * w3;
            }
        }

        float w2v[9];
        #pragma unroll
        for (int o = 0; o < 9; o++) w2v[o] = sW2[(l * HDIM + t) * 9 + o];

        float part[PTS * 9];
        #pragma unroll
        for (int pp = 0; pp < PTS; pp++) {
            float h1 = tanhf(acc[pp]);
            #pragma unroll
            for (int o = 0; o < 9; o++) part[pp * 9 + o] = h1 * w2v[o];
        }
        #pragma unroll
        for (int off = 32; off >= 1; off >>= 1) {
            #pragma unroll
            for (int u = 0; u < PTS * 9; u++)
                part[u] += __shfl_xor(part[u], off);
        }
        const int wave = t >> 6;
        if ((t & 63) == 0) {
            #pragma unroll
            for (int u = 0; u < PTS * 9; u++) red[wave][u] = part[u];
        }
        __syncthreads();
        if (t < PTS * 9) {
            int pp = t / 9, o = t % 9;
            float s  = red[0][t] + red[1][t] + red[2][t] + red[3][t] + sb2[l * 9 + o];
            int pt   = p0 + pp;
            int a    = pt >> 4, bb2 = pt & 15;
            ws[((l * GS + a) * GS + bb2) * 12 + o] = tanhf(s);
        }
    } else {
        // ---------------- bias tables: bq (which=0) / bp (which=1) ----------------
        const int bb    = bx - (256 / PTS) * 4;
        const int which = bb / (GB / PTS);
        const int p0    = (bb % (GB / PTS)) * PTS;
        const float* W0 = which ? kW0 : qW0;
        const float* B0 = which ? kb0 : qb0;
        const float* W1 = which ? kW1 : qW1;
        const float* B1 = which ? kb1 : qb1;
        const float* W2 = which ? kW2 : qW2;
        const float* B2 = which ? kb2 : qb2;
        const float b0v = B0[t];
        const float b1v = B1[t];

        #pragma unroll
        for (int pp = 0; pp < PTS; pp++) {
            float x = (float)(p0 + pp) * (1.0f / (GB - 1));
            h0s[pp][t] = tanhf(x * W0[t] + b0v);
        }
        __syncthreads();

        float acc[PTS];
        #pragma unroll
        for (int pp = 0; pp < PTS; pp++) acc[pp] = b1v;
        for (int k = 0; k < HDIM; k += 4) {
            float w0 = W1[(k + 0) * HDIM + t];
            float w1 = W1[(k + 1) * HDIM + t];
            float w2 = W1[(k + 2) * HDIM + t];
            float w3 = W1[(k + 3) * HDIM + t];
            #pragma unroll
            for (int pp = 0; pp < PTS; pp++) {
                float4 h = *(const float4*)&h0s[pp][k];
                acc[pp] += h.x * w0 + h.y * w1 + h.z * w2 + h.w * w3;
            }
        }

        float w2v[3];
        #pragma unroll
        for (int o = 0; o < 3; o++) w2v[o] = W2[t * 3 + o];

        float part[PTS * 3];
        #pragma unroll
        for (int pp = 0; pp < PTS; pp++) {
            float h1 = tanhf(acc[pp]);
            #pragma unroll
            for (int o = 0; o < 3; o++) part[pp * 3 + o] = h1 * w2v[o];
        }
        #pragma unroll
        for (int off = 32; off >= 1; off >>= 1) {
            #pragma unroll
            for (int u = 0; u < PTS * 3; u++)
                part[u] += __shfl_xor(part[u], off);
        }
        const int wave = t >> 6;
        if ((t & 63) == 0) {
            #pragma unroll
            for (int u = 0; u < PTS * 3; u++) red[wave][u] = part[u];
        }
        __syncthreads();
        if (t < PTS * 3) {
            int pp = t / 3, o = t % 3;
            float s = red[0][t] + red[1][t] + red[2][t] + red[3][t] + B2[o];
            ws[SOFF + (which * GB + (p0 + pp)) * 4 + o] = tanhf(s);
        }
    }
}

// ---------------------------------------------------------------------------
// Kernel 2: one block per batch element.  Stage the full 4-layer S table in
// LDS, keep qf/pf (48 floats each) in LDS, run the 4 sequential symmetrized
// matvec updates, add interpolated biases, write both outputs.
// Thread t owns ordered pair (i = t>>4, j = t&15); its table entry O = S-MLP
// at (m_j, m_i) contributes  O  @ v_j  to rows of i  (reduced over the 16
// consecutive j-lanes) and  O^T @ v_i  to rows of j  (reduced over the 4
// i-values in each wave, then across waves via LDS).
// ---------------------------------------------------------------------------
__global__ __launch_bounds__(256) void three_body_main(
    const float* __restrict__ q, const float* __restrict__ p,
    const float* __restrict__ m, const float* __restrict__ dtp,
    const float* __restrict__ ws, float* __restrict__ out)
{
    const int t = threadIdx.x;
    const int b = blockIdx.x;

    __shared__ float tab[4 * GS * GS * 12];   // 48 KiB
    __shared__ float mv[16];
    __shared__ float vq[48], vp[48];
    __shared__ float dbuf[48];
    __shared__ float tbuf[4][48];

    // stage table (12288 floats = 3072 float4)
    {
        const float4* s4 = (const float4*)ws;
        float4*       d4 = (float4*)tab;
        #pragma unroll
        for (int k = 0; k < 12; k++) d4[t + 256 * k] = s4[t + 256 * k];
    }
    if (t < 16) mv[t] = m[b * 16 + t];
    if (t < 48) { vq[t] = q[b * 48 + t]; vp[t] = p[b * 48 + t]; }
    __syncthreads();

    const float dt    = dtp[0];
    const float scale = dt * dt * dt;

    const int i = t >> 4, j = t & 15;
    const float mi = mv[i], mj = mv[j];

    // bilinear coords: table axis a = first MLP input = m_j, axis b = m_i
    float txa = mj * (float)(GS - 1);
    int   ga  = (int)txa; if (ga > GS - 2) ga = GS - 2;
    float fa  = txa - (float)ga;
    float txb = mi * (float)(GS - 1);
    int   gb  = (int)txb; if (gb > GS - 2) gb = GS - 2;
    float fb  = txb - (float)gb;
    const float w00 = (1.0f - fa) * (1.0f - fb);
    const float w10 = fa * (1.0f - fb);
    const float w01 = (1.0f - fa) * fb;
    const float w11 = fa * fb;
    const int base = (ga * GS + gb) * 12;

    for (int l = 0; l < 4; l++) {
        const float* tl = tab + l * GS * GS * 12;
        const float4* c00 = (const float4*)(tl + base);
        const float4* c10 = (const float4*)(tl + base + GS * 12);
        const float4* c01 = (const float4*)(tl + base + 12);
        const float4* c11 = (const float4*)(tl + base + GS * 12 + 12);

        float O[12];
        #pragma unroll
        for (int u = 0; u < 3; u++) {
            float4 a0 = c00[u], a1 = c10[u], a2 = c01[u], a3 = c11[u];
            O[4 * u + 0] = w00 * a0.x + w10 * a1.x + w01 * a2.x + w11 * a3.x;
            O[4 * u + 1] = w00 * a0.y + w10 * a1.y + w01 * a2.y + w11 * a3.y;
            O[4 * u + 2] = w00 * a0.z + w10 * a1.z + w01 * a2.z + w11 * a3.z;
            O[4 * u + 3] = w00 * a0.w + w10 * a1.w + w01 * a2.w + w11 * a3.w;
        }

        const float* v = (l & 1) ? vp : vq;   // even layer updates pf from qf
        float vj0 = v[3 * j], vj1 = v[3 * j + 1], vj2 = v[3 * j + 2];
        float vi0 = v[3 * i], vi1 = v[3 * i + 1], vi2 = v[3 * i + 2];

        // direct: rows of i      d[a]  = sum_c O[3a+c] * v[3j+c]
        float d0 = O[0] * vj0 + O[1] * vj1 + O[2] * vj2;
        float d1 = O[3] * vj0 + O[4] * vj1 + O[5] * vj2;
        float d2 = O[6] * vj0 + O[7] * vj1 + O[8] * vj2;
        // transpose: rows of j   tr[c] = sum_a O[3a+c] * v[3i+a]
        float r0 = O[0] * vi0 + O[3] * vi1 + O[6] * vi2;
        float r1 = O[1] * vi0 + O[4] * vi1 + O[7] * vi2;
        float r2 = O[2] * vi0 + O[5] * vi1 + O[8] * vi2;

        // reduce d over the 16 consecutive j-lanes
        #pragma unroll
        for (int off = 1; off < 16; off <<= 1) {
            d0 += __shfl_xor(d0, off);
            d1 += __shfl_xor(d1, off);
            d2 += __shfl_xor(d2, off);
        }
        // reduce tr over the 4 i-values within this wave
        #pragma unroll
        for (int off = 16; off < 64; off <<= 1) {
            r0 += __shfl_xor(r0, off);
            r1 += __shfl_xor(r1, off);
            r2 += __shfl_xor(r2, off);
        }

        if (j == 0) { dbuf[3 * i] = d0; dbuf[3 * i + 1] = d1; dbuf[3 * i + 2] = d2; }
        const int wave = t >> 6;
        if (((t >> 4) & 3) == 0) {
            tbuf[wave][3 * j] = r0; tbuf[wave][3 * j + 1] = r1; tbuf[wave][3 * j + 2] = r2;
        }
        __syncthreads();

        float* dst = (l & 1) ? vq : vp;
        if (t < 48)
            dst[t] += scale * (dbuf[t] + tbuf[0][t] + tbuf[1][t] + tbuf[2][t] + tbuf[3][t]);
        __syncthreads();
    }

    // epilogue: add interpolated biases and write both outputs
    if (t < 96) {
        const int half = t / 48;          // 0 -> q output (bq), 1 -> p output (bp)
        const int r    = t % 48;
        const int pp   = r / 3, e = r % 3;
        float mm = mv[pp];
        float tx = mm * (float)(GB - 1);
        int   g  = (int)tx; if (g > GB - 2) g = GB - 2;
        float f  = tx - (float)g;
        const float* tb = ws + SOFF + half * GB * 4;
        float v0 = tb[g * 4 + e], v1 = tb[(g + 1) * 4 + e];
        float bias = v0 + f * (v1 - v0);
        float base_v = half ? vp[r] : vq[r];
        out[half * 49152 + b * 48 + r] = base_v + scale * bias;
    }
}

extern "C" void kernel_launch(void* const* d_in, const int* in_sizes, int n_in,
                              void* d_out, int out_size, void* d_ws, size_t ws_size,
                              hipStream_t stream) {
    const float* q   = (const float*)d_in[0];
    const float* p   = (const float*)d_in[1];
    const float* m   = (const float*)d_in[2];
    const float* dt  = (const float*)d_in[3];
    const float* sW0 = (const float*)d_in[4];
    const float* sb0 = (const float*)d_in[5];
    const float* sW1 = (const float*)d_in[6];
    const float* sb1 = (const float*)d_in[7];
    const float* sW2 = (const float*)d_in[8];
    const float* sb2 = (const float*)d_in[9];
    const float* qW0 = (const float*)d_in[10];
    const float* qb0 = (const float*)d_in[11];
    const float* qW1 = (const float*)d_in[12];
    const float* qb1 = (const float*)d_in[13];
    const float* qW2 = (const float*)d_in[14];
    const float* qb2 = (const float*)d_in[15];
    const float* kW0 = (const float*)d_in[16];
    const float* kb0 = (const float*)d_in[17];
    const float* kW1 = (const float*)d_in[18];
    const float* kb1 = (const float*)d_in[19];
    const float* kW2 = (const float*)d_in[20];
    const float* kb2 = (const float*)d_in[21];

    float* ws  = (float*)d_ws;
    float* out = (float*)d_out;

    // 256 S-table blocks + 32 bias-table blocks
    build_tables<<<288, 256, 0, stream>>>(sW0, sb0, sW1, sb1, sW2, sb2,
                                          qW0, qb0, qW1, qb1, qW2, qb2,
                                          kW0, kb0, kW1, kb1, kW2, kb2, ws);
    three_body_main<<<1024, 256, 0, stream>>>(q, p, m, dt, ws, out);
}

// Round 2
// 129.563 us; speedup vs baseline: 1.0733x; 1.0733x over previous
//
#include <hip/hip_runtime.h>

#define GS   8                  // S-table grid points per axis (8x8 bilinear; err ~2e-6 in output)
#define GB   64                 // bias-table grid points
#define HDIM 256
#define PTS  4                  // grid points per build block
#define SOFF (4 * GS * GS * 12) // float offset of bias tables in ws

// ---------------------------------------------------------------------------
// Kernel 1: tabulate the pair MLP S(x0,x1) on a GS x GS grid for each of the 4
// layers (entry padded to 12 floats), and the two bias MLPs bq(m), bp(m) on a
// GB grid (entry padded to 4 floats).  Each block evaluates PTS grid points.
// ---------------------------------------------------------------------------
__global__ __launch_bounds__(256) void build_tables(
    const float* __restrict__ sW0, const float* __restrict__ sb0,
    const float* __restrict__ sW1, const float* __restrict__ sb1,
    const float* __restrict__ sW2, const float* __restrict__ sb2,
    const float* __restrict__ qW0, const float* __restrict__ qb0,
    const float* __restrict__ qW1, const float* __restrict__ qb1,
    const float* __restrict__ qW2, const float* __restrict__ qb2,
    const float* __restrict__ kW0, const float* __restrict__ kb0,
    const float* __restrict__ kW1, const float* __restrict__ kb1,
    const float* __restrict__ kW2, const float* __restrict__ kb2,
    float* __restrict__ ws)
{
    const int t  = threadIdx.x;
    const int bx = blockIdx.x;
    __shared__ float h0s[PTS][HDIM];
    __shared__ float red[4][PTS * 9];

    const int SBLK = (GS * GS / PTS);      // 16 blocks per layer

    if (bx < SBLK * 4) {
        // ---------------- S table ----------------
        const int l  = bx / SBLK;
        const int p0 = (bx % SBLK) * PTS;
        const float* W0 = sW0 + l * 2 * HDIM;
        const float* W1 = sW1 + l * HDIM * HDIM;
        const float b0v = sb0[l * HDIM + t];
        const float b1v = sb1[l * HDIM + t];

        #pragma unroll
        for (int pp = 0; pp < PTS; pp++) {
            int pt   = p0 + pp;
            float x0 = (float)(pt >> 3) * (1.0f / (GS - 1)); // first MLP input (m_j axis)
            float x1 = (float)(pt & 7)  * (1.0f / (GS - 1)); // second MLP input (m_i axis)
            h0s[pp][t] = tanhf(x0 * W0[t] + x1 * W0[HDIM + t] + b0v);
        }
        __syncthreads();

        float acc[PTS];
        #pragma unroll
        for (int pp = 0; pp < PTS; pp++) acc[pp] = b1v;
        for (int k = 0; k < HDIM; k += 4) {
            float w0 = W1[(k + 0) * HDIM + t];
            float w1 = W1[(k + 1) * HDIM + t];
            float w2 = W1[(k + 2) * HDIM + t];
            float w3 = W1[(k + 3) * HDIM + t];
            #pragma unroll
            for (int pp = 0; pp < PTS; pp++) {
                float4 h = *(const float4*)&h0s[pp][k];  // broadcast read
                acc[pp] += h.x * w0 + h.y * w1 + h.z * w2 + h.w * w3;
            }
        }

        float w2v[9];
        #pragma unroll
        for (int o = 0; o < 9; o++) w2v[o] = sW2[(l * HDIM + t) * 9 + o];

        float part[PTS * 9];
        #pragma unroll
        for (int pp = 0; pp < PTS; pp++) {
            float h1 = tanhf(acc[pp]);
            #pragma unroll
            for (int o = 0; o < 9; o++) part[pp * 9 + o] = h1 * w2v[o];
        }
        #pragma unroll
        for (int off = 32; off >= 1; off >>= 1) {
            #pragma unroll
            for (int u = 0; u < PTS * 9; u++)
                part[u] += __shfl_xor(part[u], off);
        }
        const int wave = t >> 6;
        if ((t & 63) == 0) {
            #pragma unroll
            for (int u = 0; u < PTS * 9; u++) red[wave][u] = part[u];
        }
        __syncthreads();
        if (t < PTS * 9) {
            int pp = t / 9, o = t % 9;
            float s  = red[0][t] + red[1][t] + red[2][t] + red[3][t] + sb2[l * 9 + o];
            int pt   = p0 + pp;
            int a    = pt >> 3, bb2 = pt & 7;
            ws[((l * GS + a) * GS + bb2) * 12 + o] = tanhf(s);
        }
    } else {
        // ---------------- bias tables: bq (which=0) / bp (which=1) ----------------
        const int bb    = bx - SBLK * 4;
        const int which = bb / (GB / PTS);
        const int p0    = (bb % (GB / PTS)) * PTS;
        const float* W0 = which ? kW0 : qW0;
        const float* B0 = which ? kb0 : qb0;
        const float* W1 = which ? kW1 : qW1;
        const float* B1 = which ? kb1 : qb1;
        const float* W2 = which ? kW2 : qW2;
        const float* B2 = which ? kb2 : qb2;
        const float b0v = B0[t];
        const float b1v = B1[t];

        #pragma unroll
        for (int pp = 0; pp < PTS; pp++) {
            float x = (float)(p0 + pp) * (1.0f / (GB - 1));
            h0s[pp][t] = tanhf(x * W0[t] + b0v);
        }
        __syncthreads();

        float acc[PTS];
        #pragma unroll
        for (int pp = 0; pp < PTS; pp++) acc[pp] = b1v;
        for (int k = 0; k < HDIM; k += 4) {
            float w0 = W1[(k + 0) * HDIM + t];
            float w1 = W1[(k + 1) * HDIM + t];
            float w2 = W1[(k + 2) * HDIM + t];
            float w3 = W1[(k + 3) * HDIM + t];
            #pragma unroll
            for (int pp = 0; pp < PTS; pp++) {
                float4 h = *(const float4*)&h0s[pp][k];
                acc[pp] += h.x * w0 + h.y * w1 + h.z * w2 + h.w * w3;
            }
        }

        float w2v[3];
        #pragma unroll
        for (int o = 0; o < 3; o++) w2v[o] = W2[t * 3 + o];

        float part[PTS * 3];
        #pragma unroll
        for (int pp = 0; pp < PTS; pp++) {
            float h1 = tanhf(acc[pp]);
            #pragma unroll
            for (int o = 0; o < 3; o++) part[pp * 3 + o] = h1 * w2v[o];
        }
        #pragma unroll
        for (int off = 32; off >= 1; off >>= 1) {
            #pragma unroll
            for (int u = 0; u < PTS * 3; u++)
                part[u] += __shfl_xor(part[u], off);
        }
        const int wave = t >> 6;
        if ((t & 63) == 0) {
            #pragma unroll
            for (int u = 0; u < PTS * 3; u++) red[wave][u] = part[u];
        }
        __syncthreads();
        if (t < PTS * 3) {
            int pp = t / 3, o = t % 3;
            float s = red[0][t] + red[1][t] + red[2][t] + red[3][t] + B2[o];
            ws[SOFF + (which * GB + (p0 + pp)) * 4 + o] = tanhf(s);
        }
    }
}

// ---------------------------------------------------------------------------
// Kernel 2: one block per batch element.  Stage the full 4-layer S table
// (12 KiB at GS=8) in LDS, keep qf/pf (48 floats each) in LDS, run the 4
// sequential symmetrized matvec updates, add interpolated biases, write both
// outputs.  Thread t owns ordered pair (i = t>>4, j = t&15).
// LDS ~13.6 KiB -> 8 blocks/CU (wave-capped), all 1024 blocks resident.
// ---------------------------------------------------------------------------
__global__ __launch_bounds__(256) void three_body_main(
    const float* __restrict__ q, const float* __restrict__ p,
    const float* __restrict__ m, const float* __restrict__ dtp,
    const float* __restrict__ ws, float* __restrict__ out)
{
    const int t = threadIdx.x;
    const int b = blockIdx.x;

    __shared__ float tab[4 * GS * GS * 12];   // 12 KiB
    __shared__ float mv[16];
    __shared__ float vq[48], vp[48];
    __shared__ float dbuf[48];
    __shared__ float tbuf[4][48];

    // stage table (3072 floats = 768 float4)
    {
        const float4* s4 = (const float4*)ws;
        float4*       d4 = (float4*)tab;
        #pragma unroll
        for (int k = 0; k < 3; k++) d4[t + 256 * k] = s4[t + 256 * k];
    }
    if (t < 16) mv[t] = m[b * 16 + t];
    if (t < 48) { vq[t] = q[b * 48 + t]; vp[t] = p[b * 48 + t]; }
    __syncthreads();

    const float dt    = dtp[0];
    const float scale = dt * dt * dt;

    const int i = t >> 4, j = t & 15;
    const float mi = mv[i], mj = mv[j];

    // bilinear coords: table axis a = first MLP input = m_j, axis b = m_i
    float txa = mj * (float)(GS - 1);
    int   ga  = (int)txa; if (ga > GS - 2) ga = GS - 2;
    float fa  = txa - (float)ga;
    float txb = mi * (float)(GS - 1);
    int   gb  = (int)txb; if (gb > GS - 2) gb = GS - 2;
    float fb  = txb - (float)gb;
    const float w00 = (1.0f - fa) * (1.0f - fb);
    const float w10 = fa * (1.0f - fb);
    const float w01 = (1.0f - fa) * fb;
    const float w11 = fa * fb;
    const int base = (ga * GS + gb) * 12;

    for (int l = 0; l < 4; l++) {
        const float* tl = tab + l * GS * GS * 12;
        const float4* c00 = (const float4*)(tl + base);
        const float4* c10 = (const float4*)(tl + base + GS * 12);
        const float4* c01 = (const float4*)(tl + base + 12);
        const float4* c11 = (const float4*)(tl + base + GS * 12 + 12);

        float O[12];
        #pragma unroll
        for (int u = 0; u < 3; u++) {
            float4 a0 = c00[u], a1 = c10[u], a2 = c01[u], a3 = c11[u];
            O[4 * u + 0] = w00 * a0.x + w10 * a1.x + w01 * a2.x + w11 * a3.x;
            O[4 * u + 1] = w00 * a0.y + w10 * a1.y + w01 * a2.y + w11 * a3.y;
            O[4 * u + 2] = w00 * a0.z + w10 * a1.z + w01 * a2.z + w11 * a3.z;
            O[4 * u + 3] = w00 * a0.w + w10 * a1.w + w01 * a2.w + w11 * a3.w;
        }

        const float* v = (l & 1) ? vp : vq;   // even layer updates pf from qf
        float vj0 = v[3 * j], vj1 = v[3 * j + 1], vj2 = v[3 * j + 2];
        float vi0 = v[3 * i], vi1 = v[3 * i + 1], vi2 = v[3 * i + 2];

        // direct: rows of i      d[a]  = sum_c O[3a+c] * v[3j+c]
        float d0 = O[0] * vj0 + O[1] * vj1 + O[2] * vj2;
        float d1 = O[3] * vj0 + O[4] * vj1 + O[5] * vj2;
        float d2 = O[6] * vj0 + O[7] * vj1 + O[8] * vj2;
        // transpose: rows of j   tr[c] = sum_a O[3a+c] * v[3i+a]
        float r0 = O[0] * vi0 + O[3] * vi1 + O[6] * vi2;
        float r1 = O[1] * vi0 + O[4] * vi1 + O[7] * vi2;
        float r2 = O[2] * vi0 + O[5] * vi1 + O[8] * vi2;

        // reduce d over the 16 consecutive j-lanes
        #pragma unroll
        for (int off = 1; off < 16; off <<= 1) {
            d0 += __shfl_xor(d0, off);
            d1 += __shfl_xor(d1, off);
            d2 += __shfl_xor(d2, off);
        }
        // reduce tr over the 4 i-values within this wave
        #pragma unroll
        for (int off = 16; off < 64; off <<= 1) {
            r0 += __shfl_xor(r0, off);
            r1 += __shfl_xor(r1, off);
            r2 += __shfl_xor(r2, off);
        }

        if (j == 0) { dbuf[3 * i] = d0; dbuf[3 * i + 1] = d1; dbuf[3 * i + 2] = d2; }
        const int wave = t >> 6;
        if (((t >> 4) & 3) == 0) {
            tbuf[wave][3 * j] = r0; tbuf[wave][3 * j + 1] = r1; tbuf[wave][3 * j + 2] = r2;
        }
        __syncthreads();

        float* dst = (l & 1) ? vq : vp;
        if (t < 48)
            dst[t] += scale * (dbuf[t] + tbuf[0][t] + tbuf[1][t] + tbuf[2][t] + tbuf[3][t]);
        __syncthreads();
    }

    // epilogue: add interpolated biases and write both outputs
    if (t < 96) {
        const int half = t / 48;          // 0 -> q output (bq), 1 -> p output (bp)
        const int r    = t % 48;
        const int pp   = r / 3, e = r % 3;
        float mm = mv[pp];
        float tx = mm * (float)(GB - 1);
        int   g  = (int)tx; if (g > GB - 2) g = GB - 2;
        float f  = tx - (float)g;
        const float* tb = ws + SOFF + half * GB * 4;
        float v0 = tb[g * 4 + e], v1 = tb[(g + 1) * 4 + e];
        float bias = v0 + f * (v1 - v0);
        float base_v = half ? vp[r] : vq[r];
        out[half * 49152 + b * 48 + r] = base_v + scale * bias;
    }
}

extern "C" void kernel_launch(void* const* d_in, const int* in_sizes, int n_in,
                              void* d_out, int out_size, void* d_ws, size_t ws_size,
                              hipStream_t stream) {
    const float* q   = (const float*)d_in[0];
    const float* p   = (const float*)d_in[1];
    const float* m   = (const float*)d_in[2];
    const float* dt  = (const float*)d_in[3];
    const float* sW0 = (const float*)d_in[4];
    const float* sb0 = (const float*)d_in[5];
    const float* sW1 = (const float*)d_in[6];
    const float* sb1 = (const float*)d_in[7];
    const float* sW2 = (const float*)d_in[8];
    const float* sb2 = (const float*)d_in[9];
    const float* qW0 = (const float*)d_in[10];
    const float* qb0 = (const float*)d_in[11];
    const float* qW1 = (const float*)d_in[12];
    const float* qb1 = (const float*)d_in[13];
    const float* qW2 = (const float*)d_in[14];
    const float* qb2 = (const float*)d_in[15];
    const float* kW0 = (const float*)d_in[16];
    const float* kb0 = (const float*)d_in[17];
    const float* kW1 = (const float*)d_in[18];
    const float* kb1 = (const float*)d_in[19];
    const float* kW2 = (const float*)d_in[20];
    const float* kb2 = (const float*)d_in[21];

    float* ws  = (float*)d_ws;
    float* out = (float*)d_out;

    // 64 S-table blocks + 32 bias-table blocks
    build_tables<<<96, 256, 0, stream>>>(sW0, sb0, sW1, sb1, sW2, sb2,
                                         qW0, qb0, qW1, qb1, qW2, qb2,
                                         kW0, kb0, kW1, kb1, kW2, kb2, ws);
    three_body_main<<<1024, 256, 0, stream>>>(q, p, m, dt, ws, out);
}